// Round 16
// baseline (836.197 us; speedup 1.0000x reference)
//
#include <hip/hip_runtime.h>
#include <cmath>

#define HTOT  590
#define BATCH 4096
#define VOCAB 8192

typedef _Float16 f16;
typedef __attribute__((ext_vector_type(8))) _Float16 f16x8;
typedef __attribute__((ext_vector_type(4))) _Float16 f16x4;
typedef __attribute__((ext_vector_type(4))) float f32x4;
typedef __attribute__((ext_vector_type(16))) float f32x16;

// ---------------- workspace layout (float units) ----------------
constexpr size_t OFF_EHL  = 0;           // 1,310,720 fl: e hi/lo f16 [5][8192][64f16]
constexpr size_t OFF_WF   = 1310720;     // 53,760 fl: wfrag f16 [5][7][2][3][64][8]
constexpr size_t OFF_PA   = 1364480;     // 1,572,864: [b][192][2] pass-A stats
constexpr size_t OFF_PB   = 2937344;     // 1,572,864: [b][192][2] pooled stats
constexpr size_t OFF_BN1  = 4510208;     // 320 (SoA A[160], B[160])
constexpr size_t OFF_BNP  = 4510528;     // 320
constexpr size_t OFF_CP   = 4510848;     // 131,072 floats: colstats [2048][32][2]
constexpr size_t OFF_BNF1 = 4641920;     // 4,096
constexpr size_t OFF_PRAW = 4646016;     // 7,864,320: p fp32 -> packed {hi,lo} f16 in place
constexpr size_t OFF_W1P  = 12510336;    // 1,966,080 (f16)
constexpr size_t OFF_W2P  = 14476416;    // 2,097,152 (f16)
constexpr size_t OFF_Y    = 16573568;    // 8,388,608
constexpr size_t OFF_BNF2 = 24962176;    // 4,096
constexpr size_t OFF_Z2K  = 0;           // conv region dead by then
constexpr size_t OFF_Z3K  = 4194304;     // overlaps dead conv-era buffers (order-safe)
// END = 24,966,272 fl = 99.9MB (proven available)

__device__ __forceinline__ float qw(float w) {
  return rintf(fminf(fmaxf(w, -1.f), 1.f));
}
__device__ __forceinline__ float4 ld4(const float* p) {
  return *reinterpret_cast<const float4*>(p);
}
__device__ __forceinline__ float tanh_c(float u) {
  const float e = __expf(2.f*u);
  return 1.f - __fdividef(2.f, e + 1.f);
}

#define MF(A,B,C) __builtin_amdgcn_mfma_f32_32x32x16_f16(A,B,C,0,0,0)
// w-frag fetch: variant V: 0=wh*2048, 1=(w-wh)*2048, 2=wh
#define WV(K,KS,V) (*reinterpret_cast<const f16x8*>(wfsl + (((K)*2+(KS))*3+(V))*256 + lane*4))

// ---------------- merged prep: e-table (blocks 0..5119) + w-frags (5120..5539) ----------------
__global__ __launch_bounds__(256) void k_prep(const float* __restrict__ emb,
                                              const float* __restrict__ convw,
                                              f16* __restrict__ ehl,
                                              f16* __restrict__ wf)
{
  const int bid = blockIdx.x;
  const int tid = threadIdx.x;
  if (bid < 5120) {
    const int idx = bid*256 + tid;                  // exactly 1,310,720
    const int c = idx & 31, v = (idx >> 5) & 8191, slice = idx >> 18;
    const float val = emb[(size_t)(slice*VOCAB + v)*32 + c];
    const f16 hi = (f16)val;
    const f16 lo = (f16)((val - (float)hi)*2048.f);
    f16* row = ehl + (size_t)(slice*VOCAB + v)*64;
    row[c] = hi; row[32 + c] = lo;
  } else {
    const int idx = (bid - 5120)*256 + tid;         // exactly 107,520
    const int j = idx & 7, lane = (idx >> 3) & 63;
    const int rest = idx >> 9;
    const int v = rest % 3;
    const int rest2 = rest / 3;
    const int ks = rest2 & 1, kk = rest2 >> 1;
    const int k = kk % 7, slice = kk / 7;
    const int f = lane & 31, c = ks*16 + (lane >> 5)*8 + j;
    const float val = convw[((slice*32 + f)*32 + c)*7 + k];
    const f16 hi = (f16)val;
    f16 o;
    if (v == 0)      o = (f16)((float)hi * 2048.f); // exact: exponent shift
    else if (v == 1) o = (f16)((val - (float)hi)*2048.f);
    else             o = hi;
    wf[idx] = o;
  }
}

// ---------------- MFMA conv (single scaled accumulator, reg-staged gather) ----------------
// PASS 0: BN1 stats via f16 hstat transpose (r8-validated).
// PASS 1: BN1 + tanh + avgpool -> z + pooled stats.
// acc = sum over k,ks of [wh2*eh + wl*eh + wh*el] == 2048*h; h = acc/2048.
template<int PASS>
__global__ __launch_bounds__(256, 4) void k_convm(const int* __restrict__ x,
                                                  const int* __restrict__ gshift,
                                                  const float* __restrict__ ehl,
                                                  const float* __restrict__ wfrag,
                                                  const float* __restrict__ bn1,
                                                  float* __restrict__ z,
                                                  float* __restrict__ partials)
{
  const int b = blockIdx.x;
  const int type = blockIdx.y;                      // 0..3
  const int tid = threadIdx.x;
  const int wid = tid >> 6, lane = tid & 63;
  const int lt = lane & 31, hf = lane >> 5;

  __shared__ float smem[9408];
  __shared__ int   tokoff[294];                     // pre-scaled (sl*VOCAB+tok)*32 fl-offset

  float* tokarr = smem;
  f16*   hstat  = (f16*)smem;
  float* part2  = smem + 6000;
  float* thbuf  = smem;
  float* poolb  = smem + 4224;

  const int gsv = gshift[b];
  const int NTOK = (type == 0) ? 270 : 294;

  // ---- stage token ids -> pre-scaled e-table offsets (padded to 294) ----
  for (int i = tid; i < 294; i += 256) {
    int off = 0;                                    // pad rows: valid addr, junk never read
    if (i < NTOK) {
      int xs, q = i, sl;
      if (type == 0) {
        if (i < 42)       { xs = 548; sl = 0; }
        else if (i < 120) { xs = 512; q = i - 42; sl = 1; }
        else              { xs = 440 - gsv % 12; q = i - 120; sl = 2; }
      } else if (type == 1) { xs = 296 - gsv % 24; sl = 3; }
      else if (type == 2)   { xs = 8 - gsv % 48; sl = 4; }
      else                  { xs = 8 - gsv % 48 + 288; sl = 4; }
      int xi = xs + q; if (xi < 0) xi += HTOT;
      off = (sl*VOCAB + x[b*HTOT + xi])*32;
    }
    tokoff[i] = off;
  }
  __syncthreads();
  // ---- gather e rows: reg-staged, linear LDS dest (j*16B; layout identical to r14) ----
  for (int j = tid; j < 2352; j += 256) {
    const int ch = j / 294;
    const int row = j - ch*294;
    *reinterpret_cast<float4*>(&tokarr[j*4]) = ld4(ehl + tokoff[row] + ch*4);
  }
  __syncthreads();

  // ---- per-wave work assignment ----
  int slice, tb, nt, slotoff, ThV, pw, si;
  if (type == 0) {
    if      (wid == 0) { slice=0; tb=0;  nt=2; slotoff=0;   ThV=36;  pw=3;  si=0; }
    else if (wid == 1) { slice=1; tb=0;  nt=3; slotoff=42;  ThV=72;  pw=6;  si=1; }
    else if (wid == 2) { slice=2; tb=0;  nt=3; slotoff=120; ThV=144; pw=12; si=2; }
    else               { slice=2; tb=96; nt=2; slotoff=120; ThV=144; pw=12; si=2; }
  } else if (type == 1) {
    slice=3; pw=24; ThV=288; slotoff=0; si=0;
    tb = (wid == 0) ? 0 : 32 + wid*64; nt = (wid == 0) ? 3 : 2;
  } else if (type == 2) {
    slice=4; pw=48; ThV=288; slotoff=0; si=0;
    tb = (wid == 0) ? 0 : 32 + wid*64; nt = (wid == 0) ? 3 : 2;
  } else {
    slice=4; pw=48; ThV=576; slotoff=-288; si=0;
    tb = 288 + ((wid == 0) ? 0 : 32 + wid*64); nt = (wid == 0) ? 3 : 2;
  }
  const int wb = (type == 3) ? 6 : 0;
  const int slot0 = (type == 0) ? ((wid == 0) ? 0 : (wid == 1) ? 2 : (wid == 2) ? 5 : 8)
                                : ((wid == 0) ? 0 : 1 + wid*2);

  const float* wfsl = wfrag + slice*10752;          // 7*2*3*64*8 f16 = 10752 fl per slice

  f32x16 acc[3];
  #pragma unroll
  for (int r = 0; r < 3; ++r)
    #pragma unroll
    for (int i = 0; i < 16; ++i) acc[r][i] = 0.f;

  // ---- K loop ----
  const float* pb = tokarr + hf*1176 + (size_t)(slotoff + tb + lt)*4;
  #pragma unroll 1
  for (int k = 0; k < 7; ++k) {
    const f16x8 wh2_0 = WV(k,0,0), wl_0 = WV(k,0,1), wh_0 = WV(k,0,2);
    const f16x8 wh2_1 = WV(k,1,0), wl_1 = WV(k,1,1), wh_1 = WV(k,1,2);
    #pragma unroll
    for (int r = 0; r < 3; ++r) if (r < nt) {
      const float* rp = pb + k*4 + r*128;
      const f16x8 bh0 = *(const f16x8*)(rp);
      const f16x8 bh1 = *(const f16x8*)(rp + 2352);
      const f16x8 bl0 = *(const f16x8*)(rp + 4704);
      const f16x8 bl1 = *(const f16x8*)(rp + 7056);
      acc[r] = MF(wh2_0, bh0, acc[r]);
      acc[r] = MF(wl_0,  bh0, acc[r]);
      acc[r] = MF(wh_0,  bl0, acc[r]);
      acc[r] = MF(wh2_1, bh1, acc[r]);
      acc[r] = MF(wl_1,  bh1, acc[r]);
      acc[r] = MF(wh_1,  bl1, acc[r]);
    }
  }
  __syncthreads();                                  // tokarr dead -> epilogue buffers

  if (PASS == 0) {
    // ---- stats via f16 LDS transpose (validated noise class) ----
    #pragma unroll
    for (int r = 0; r < 3; ++r) if (r < nt) {
      const int tbg = tb + r*32;
      const int slot = slot0 + r;
      #pragma unroll
      for (int i = 0; i < 16; ++i) {
        const int fr = (i&3) + 8*(i>>2) + 4*hf;
        const float h = acc[r][i]*(1.f/2048.f);
        const float hv = (tbg + lt < ThV) ? h : 0.f;
        hstat[slot*1088 + fr*34 + lt] = (f16)hv;
      }
    }
    __syncthreads();
    const int nslot = (type == 0) ? 10 : 9;
    for (int j = tid; j < nslot*32; j += 256) {
      const int slot = j >> 5, f = j & 31;
      const f16* rowp = hstat + slot*1088 + f*34;
      float s1 = 0.f, s2 = 0.f;
      #pragma unroll
      for (int t = 0; t < 32; ++t) { const float v = (float)rowp[t]; s1 += v; s2 += v*v; }
      part2[(slot*32 + f)*2]     = s1;
      part2[(slot*32 + f)*2 + 1] = s2;
    }
    __syncthreads();
    const int nch = (type == 0) ? 96 : 32;
    if (tid < nch) {
      const int sic = tid >> 5, f = tid & 31;
      int slo, shi, Pb;
      if (type == 0) {
        slo = (sic == 0) ? 0 : (sic == 1) ? 2 : 5;
        shi = (sic == 0) ? 2 : (sic == 1) ? 5 : 10;
        Pb  = sic*32;
      } else { slo = 0; shi = 9; Pb = 96 + (type - 1)*32; }
      float s1 = 0.f, s2 = 0.f;
      for (int s = slo; s < shi; ++s) {
        s1 += part2[(s*32 + f)*2];
        s2 += part2[(s*32 + f)*2 + 1];
      }
      partials[(size_t)b*384 + (Pb + f)*2]     = s1;
      partials[(size_t)b*384 + (Pb + f)*2 + 1] = s2;
    }
    return;
  }

  // ---- PASS 1: BN1 + tanh + pool (poolb init via exclusive-ownership writes) ----
  float A1v[16], B1v[16];
  #pragma unroll
  for (int i = 0; i < 16; ++i) {
    const int fr = (i&3) + 8*(i>>2) + 4*hf;
    A1v[i] = bn1[slice*32 + fr];
    B1v[i] = bn1[160 + slice*32 + fr];
  }

  #pragma unroll
  for (int r = 0; r < 3; ++r) if (r < nt) {
    const int tbg = tb + r*32;
    #pragma unroll
    for (int i = 0; i < 16; ++i) {
      const int fr = (i&3) + 8*(i>>2) + 4*hf;
      const float h = acc[r][i]*(1.f/2048.f);
      thbuf[wid*1056 + fr*33 + lt] = tanh_c(A1v[i]*h + B1v[i]);
    }
    const int tvend = min(tbg + 32, ThV);
    const int wlo = tbg / pw, whi = (tvend - 1) / pw;
    for (int w = wlo; w <= whi; ++w) {
      const int lo = max(w*pw, tbg), hi2 = min((w+1)*pw, tvend);
      float s = 0.f;
      for (int t = lo + hf; t < hi2; t += 2) s += thbuf[wid*1056 + lt*33 + (t - tbg)];
      s += __shfl_xor(s, 32);
      if (hf == 0) {
        const int piece = (w*pw < tbg) ? 1 : 0;
        poolb[(si*12 + (w - wb))*64 + piece*32 + lt] = s;
        // window fully inside my region -> no later tile writes piece1: zero it here.
        if (piece == 0 && (w+1)*pw <= tvend)
          poolb[(si*12 + (w - wb))*64 + 32 + lt] = 0.f;
      }
    }
  }
  __syncthreads();

  const int nch = (type == 0) ? 96 : 32;
  if (tid < nch) {
    const int sic = tid >> 5, f = tid & 31;
    const int sg = (type == 0) ? sic : ((type == 1) ? 3 : 4);
    const int P = (sg < 4) ? sg*32 + f : ((type == 2) ? 128 + f : 160 + f);
    const int pwc = (type == 0) ? ((sic == 0) ? 3 : (sic == 1) ? 6 : 12)
                                : ((type == 1) ? 24 : 48);
    const int nwin = (type >= 2) ? 6 : 12;
    const int wbc = (type == 3) ? 6 : 0;
    const float inv = 1.f/(float)pwc;
    float s1 = 0.f, s2 = 0.f;
    for (int wl = 0; wl < nwin; ++wl) {
      const float p = (poolb[(sic*12 + wl)*64 + f] + poolb[(sic*12 + wl)*64 + 32 + f]) * inv;
      z[(size_t)b*1920 + sg*384 + (wl + wbc)*32 + f] = p;
      s1 += p; s2 += p*p;
    }
    partials[(size_t)b*384 + P*2]     = s1;
    partials[(size_t)b*384 + P*2 + 1] = s2;
  }
}

// ---------------- BN stat reduce -> SoA {A=g*rstd, B=beta-A*m} ----------------
template<int PASS>
__global__ __launch_bounds__(256) void k_bnfinal(const float* __restrict__ partials,
                                                 const float* __restrict__ gamma,
                                                 const float* __restrict__ beta,
                                                 float* __restrict__ outAB)
{
  const int c = blockIdx.x;                        // 0..159
  const int slice = c >> 5, f = c & 31;
  const int tid = threadIdx.x;
  double s1 = 0.0, s2 = 0.0;
  for (int b = tid; b < BATCH; b += 256) {
    const float* p = partials + (size_t)b*384;
    if (slice < 4) { s1 += p[(slice*32+f)*2]; s2 += p[(slice*32+f)*2+1]; }
    else {
      s1 += (double)p[(128+f)*2]   + (double)p[(160+f)*2];
      s2 += (double)p[(128+f)*2+1] + (double)p[(160+f)*2+1];
    }
  }
  __shared__ double r1[256], r2[256];
  r1[tid] = s1; r2[tid] = s2;
  __syncthreads();
  for (int off = 128; off > 0; off >>= 1) {
    if (tid < off) { r1[tid] += r1[tid+off]; r2[tid] += r2[tid+off]; }
    __syncthreads();
  }
  if (tid == 0) {
    long N;
    if (PASS == 0) { const long Tall[5] = {36,72,144,288,576}; N = (long)BATCH * Tall[slice]; }
    else           { N = (long)BATCH * 12; }
    const double m   = r1[0]/(double)N;
    const double var = r2[0]/(double)N - m*m;
    const float rstd = (float)(1.0/sqrt(var + 1e-5));
    const float Aa = gamma[c]*rstd;
    outAB[c]       = Aa;
    outAB[160 + c] = beta[c] - Aa*(float)m;
  }
}

// ---------------- pooled BN apply + in-place f16 hi/lo pack ----------------
__global__ __launch_bounds__(256) void k_znorm(float* __restrict__ zz,
                                               const float* __restrict__ bnp)
{
  const size_t i4 = (size_t)blockIdx.x*256 + threadIdx.x;  // exactly 1,966,080
  const float4 v = ld4(zz + i4*4);
  const int j = (int)((i4*4) % 1920);
  const int slice = j / 384, f0 = j & 31;
  const float4 A = ld4(bnp + slice*32 + f0);
  const float4 B = ld4(bnp + 160 + slice*32 + f0);
  const float zn[4] = {v.x*A.x+B.x, v.y*A.y+B.y, v.z*A.z+B.z, v.w*A.w+B.w};
  uint4 pk;
  unsigned w[4];
  #pragma unroll
  for (int e = 0; e < 4; ++e) {
    const f16 hi = (f16)zn[e];
    const f16 lo = (f16)(zn[e] - (float)hi);
    w[e] = (unsigned)__builtin_bit_cast(unsigned short, hi)
         | ((unsigned)__builtin_bit_cast(unsigned short, lo) << 16);
  }
  pk.x = w[0]; pk.y = w[1]; pk.z = w[2]; pk.w = w[3];
  *reinterpret_cast<uint4*>(zz + i4*4) = pk;
}

// ---------------- weight prep ----------------
__global__ __launch_bounds__(256) void k_wprep1(const float* __restrict__ W1,
                                                f16* __restrict__ W1p)
{
  const int idx = blockIdx.x*256 + threadIdx.x;    // < 3,932,160
  const int n = idx / 1920, klds = idx - n*1920;
  const int slice = klds / 384, r = klds - slice*384;
  const int tp = r >> 5, f = r & 31;
  W1p[idx] = (f16)qw(W1[n*1920 + slice*384 + f*12 + tp]);
}

__global__ __launch_bounds__(256) void k_wprep2(const float* __restrict__ W2,
                                                f16* __restrict__ W2p)
{
  const size_t i4 = (size_t)blockIdx.x*256 + threadIdx.x;  // < 1,048,576
  const float4 v = ld4(W2 + i4*4);
  f16x4 o;
  o[0] = (f16)qw(v.x); o[1] = (f16)qw(v.y); o[2] = (f16)qw(v.z); o[3] = (f16)qw(v.w);
  *reinterpret_cast<f16x4*>(&W2p[i4*4]) = o;
}

// ---------------- MFMA GEMM with fused per-block column stats (r11-validated) ----------------
template<int SPLIT, int PACKED>
__global__ __launch_bounds__(256) void k_mfgemm(const f16* __restrict__ Ahi,
                                               const unsigned* __restrict__ Apk,
                                               const f16* __restrict__ Bp,
                                               float* __restrict__ C,
                                               float* __restrict__ cpart,
                                               const int K, const float oscale)
{
  __shared__ f16 sA[(SPLIT+1)*128][40];
  __shared__ f16 sB[128][40];
  __shared__ float cst[4][4][16][2];
  const int tid = threadIdx.x;
  const int bm = blockIdx.y*128, bn = blockIdx.x*128;
  const int wid = tid >> 6, lane = tid & 63;
  const int wm = (wid >> 1)*64, wn = (wid & 1)*64;
  const int lgrp = lane >> 4, lrow = lane & 15;
  f32x4 acc[4][4];
  #pragma unroll
  for (int m = 0; m < 4; ++m)
    #pragma unroll
    for (int n = 0; n < 4; ++n) acc[m][n] = (f32x4){0.f,0.f,0.f,0.f};

  const int srow = tid >> 2, sc = (tid & 3)*8;
  for (int k0 = 0; k0 < K; k0 += 32) {
    #pragma unroll
    for (int u = 0; u < 2; ++u) {
      const int row = srow + u*64;
      if (PACKED) {
        const unsigned* ap = Apk + (size_t)(bm+row)*K + k0 + sc;
        const uint4 v0 = *reinterpret_cast<const uint4*>(ap);
        const uint4 v1 = *reinterpret_cast<const uint4*>(ap + 4);
        uint4 hi, lo;
        hi.x = (v0.x & 0xffffu) | (v0.y << 16);  hi.y = (v0.z & 0xffffu) | (v0.w << 16);
        hi.z = (v1.x & 0xffffu) | (v1.y << 16);  hi.w = (v1.z & 0xffffu) | (v1.w << 16);
        lo.x = (v0.x >> 16) | (v0.y & 0xffff0000u);  lo.y = (v0.z >> 16) | (v0.w & 0xffff0000u);
        lo.z = (v1.x >> 16) | (v1.y & 0xffff0000u);  lo.w = (v1.z >> 16) | (v1.w & 0xffff0000u);
        *reinterpret_cast<uint4*>(&sA[row][sc])     = hi;
        *reinterpret_cast<uint4*>(&sA[128+row][sc]) = lo;
      } else {
        const uint4 va = *reinterpret_cast<const uint4*>(&Ahi[(size_t)(bm+row)*K + k0 + sc]);
        *reinterpret_cast<uint4*>(&sA[row][sc]) = va;
      }
      const uint4 vb = *reinterpret_cast<const uint4*>(&Bp[(size_t)(bn+row)*K + k0 + sc]);
      *reinterpret_cast<uint4*>(&sB[row][sc]) = vb;
    }
    __syncthreads();
    f16x8 bf[4];
    #pragma unroll
    for (int n = 0; n < 4; ++n)
      bf[n] = *reinterpret_cast<const f16x8*>(&sB[wn + n*16 + lrow][lgrp*8]);
    #pragma unroll
    for (int m = 0; m < 4; ++m) {
      const f16x8 ah = *reinterpret_cast<const f16x8*>(&sA[wm + m*16 + lrow][lgrp*8]);
      #pragma unroll
      for (int n = 0; n < 4; ++n)
        acc[m][n] = __builtin_amdgcn_mfma_f32_16x16x32_f16(ah, bf[n], acc[m][n], 0, 0, 0);
      if (SPLIT) {
        const f16x8 al = *reinterpret_cast<const f16x8*>(&sA[128 + wm + m*16 + lrow][lgrp*8]);
        #pragma unroll
        for (int n = 0; n < 4; ++n)
          acc[m][n] = __builtin_amdgcn_mfma_f32_16x16x32_f16(al, bf[n], acc[m][n], 0, 0, 0);
      }
    }
    __syncthreads();
  }
  float s1[4] = {0,0,0,0}, s2[4] = {0,0,0,0};
  #pragma unroll
  for (int m = 0; m < 4; ++m)
    #pragma unroll
    for (int n = 0; n < 4; ++n) {
      const int col = bn + wn + n*16 + lrow;
      #pragma unroll
      for (int r = 0; r < 4; ++r) {
        const float v = acc[m][n][r]*oscale;
        C[(size_t)(bm + wm + m*16 + lgrp*4 + r)*2048 + col] = v;
        s1[n] += v; s2[n] += v*v;
      }
    }
  #pragma unroll
  for (int n = 0; n < 4; ++n) {
    s1[n] += __shfl_xor(s1[n], 16); s1[n] += __shfl_xor(s1[n], 32);
    s2[n] += __shfl_xor(s2[n], 16); s2[n] += __shfl_xor(s2[n], 32);
  }
  if (lgrp == 0) {
    #pragma unroll
    for (int n = 0; n < 4; ++n) { cst[wid][n][lrow][0] = s1[n]; cst[wid][n][lrow][1] = s2[n]; }
  }
  __syncthreads();
  if (tid < 128) {
    const int n = tid >> 5, half = (tid >> 4) & 1, lr = tid & 15;
    const float a1 = cst[half][n][lr][0] + cst[half+2][n][lr][0];
    const float a2 = cst[half][n][lr][1] + cst[half+2][n][lr][1];
    const int col = bn + half*64 + n*16 + lr;
    cpart[(size_t)col*64 + blockIdx.y*2]     = a1;
    cpart[(size_t)col*64 + blockIdx.y*2 + 1] = a2;
  }
}

// ---------------- column stat finalize (32 float chunks -> BN A/B) ----------------
__global__ __launch_bounds__(256) void k_colfinal(const float* __restrict__ part,
                                                  const float* __restrict__ gamma,
                                                  const float* __restrict__ beta,
                                                  float* __restrict__ bnfc, int N)
{
  const int c = blockIdx.x*256 + threadIdx.x;
  if (c >= N) return;
  double s1 = 0.0, s2 = 0.0;
  #pragma unroll
  for (int ch = 0; ch < 32; ++ch) {
    s1 += (double)part[(size_t)c*64 + ch*2];
    s2 += (double)part[(size_t)c*64 + ch*2 + 1];
  }
  const double m   = s1/4096.0;
  const double var = s2/4096.0 - m*m;
  const float rstd = (float)(1.0/sqrt(var + 1e-5));
  const float Aa = gamma[c]*rstd;
  bnfc[c]        = Aa;
  bnfc[2048 + c] = beta[c] - Aa*(float)m;
}

// ---------------- BN + hardtanh + quantize -> integer k in f16 ----------------
__global__ __launch_bounds__(256) void k_act(const float* __restrict__ Y,
                                             const float* __restrict__ bnfc,
                                             f16* __restrict__ Zk)
{
  const size_t i4 = (size_t)blockIdx.x*256 + threadIdx.x;  // exactly 2,097,152
  const int cbase = (int)((i4*4) & 2047);
  const float4 v = ld4(Y + i4*4);
  const float4 A = ld4(bnfc + cbase);
  const float4 B = ld4(bnfc + 2048 + cbase);
  const float t[4] = {v.x*A.x+B.x, v.y*A.y+B.y, v.z*A.z+B.z, v.w*A.w+B.w};
  f16x4 o;
  #pragma unroll
  for (int e = 0; e < 4; ++e) {
    const float c = fminf(fmaxf(t[e], -1.f), 1.f);
    o[e] = (f16)rintf(c*3.f);
  }
  *reinterpret_cast<f16x4*>(&Zk[i4*4]) = o;
}

// ---------------- final dot ----------------
__global__ __launch_bounds__(256) void k_final(const f16* __restrict__ Z3,
                                               const float* __restrict__ W3,
                                               const float* __restrict__ b3,
                                               float* __restrict__ out)
{
  const int b = blockIdx.x;
  const int tid = threadIdx.x;
  float s = 0.f;
  for (int j = tid; j < 2048; j += 256)
    s += (float)Z3[(size_t)b*2048 + j] * qw(W3[j]);
  __shared__ float red[256];
  red[tid] = s;
  __syncthreads();
  for (int off = 128; off > 0; off >>= 1) {
    if (tid < off) red[tid] += red[tid+off];
    __syncthreads();
  }
  if (tid == 0) out[b] = red[0]*(1.f/3.f) + b3[0];
}

extern "C" void kernel_launch(void* const* d_in, const int* in_sizes, int n_in,
                              void* d_out, int out_size, void* d_ws, size_t ws_size,
                              hipStream_t stream)
{
  const int*   x    = (const int*)d_in[0];
  const int*   gs   = (const int*)d_in[1];
  const float* emb  = (const float*)d_in[2];
  const float* cw   = (const float*)d_in[3];
  const float* bn1g = (const float*)d_in[5];
  const float* bn1b = (const float*)d_in[6];
  const float* bnpg = (const float*)d_in[7];
  const float* bnpb = (const float*)d_in[8];
  const float* W1   = (const float*)d_in[9];
  const float* g1   = (const float*)d_in[11];
  const float* be1  = (const float*)d_in[12];
  const float* W2   = (const float*)d_in[13];
  const float* g2   = (const float*)d_in[15];
  const float* be2  = (const float*)d_in[16];
  const float* W3   = (const float*)d_in[17];
  const float* b3   = (const float*)d_in[18];
  float* ws  = (float*)d_ws;
  float* out = (float*)d_out;

  k_prep<<<5540, 256, 0, stream>>>(emb, cw, (f16*)(ws + OFF_EHL), (f16*)(ws + OFF_WF));

  k_convm<0><<<dim3(BATCH, 4), 256, 0, stream>>>(x, gs, ws + OFF_EHL, ws + OFF_WF,
                                                 ws + OFF_BN1, nullptr, ws + OFF_PA);
  k_bnfinal<0><<<160, 256, 0, stream>>>(ws + OFF_PA, bn1g, bn1b, ws + OFF_BN1);
  k_convm<1><<<dim3(BATCH, 4), 256, 0, stream>>>(x, gs, ws + OFF_EHL, ws + OFF_WF,
                                                 ws + OFF_BN1, ws + OFF_PRAW, ws + OFF_PB);
  k_bnfinal<1><<<160, 256, 0, stream>>>(ws + OFF_PB, bnpg, bnpb, ws + OFF_BNP);
  k_znorm<<<7680, 256, 0, stream>>>(ws + OFF_PRAW, ws + OFF_BNP);
  k_wprep1<<<15360, 256, 0, stream>>>(W1, (f16*)(ws + OFF_W1P));
  k_wprep2<<<4096, 256, 0, stream>>>(W2, (f16*)(ws + OFF_W2P));

  k_mfgemm<1,1><<<dim3(16, 32), 256, 0, stream>>>(nullptr, (const unsigned*)(ws + OFF_PRAW),
                                                  (const f16*)(ws + OFF_W1P),
                                                  ws + OFF_Y, ws + OFF_CP, 1920, 1.f);
  k_colfinal<<<8, 256, 0, stream>>>(ws + OFF_CP, g1, be1, ws + OFF_BNF1, 2048);
  k_act<<<8192, 256, 0, stream>>>(ws + OFF_Y, ws + OFF_BNF1, (f16*)(ws + OFF_Z2K));

  k_mfgemm<0,0><<<dim3(16, 32), 256, 0, stream>>>((const f16*)(ws + OFF_Z2K), nullptr,
                                                  (const f16*)(ws + OFF_W2P),
                                                  ws + OFF_Y, ws + OFF_CP, 2048, 1.f/3.f);
  k_colfinal<<<8, 256, 0, stream>>>(ws + OFF_CP, g2, be2, ws + OFF_BNF2, 2048);
  k_act<<<8192, 256, 0, stream>>>(ws + OFF_Y, ws + OFF_BNF2, (f16*)(ws + OFF_Z3K));

  k_final<<<4096, 256, 0, stream>>>((const f16*)(ws + OFF_Z3K), W3, b3, out);
}

// Round 17
// 758.979 us; speedup vs baseline: 1.1017x; 1.1017x over previous
//
#include <hip/hip_runtime.h>
#include <cmath>

#define HTOT  590
#define BATCH 4096
#define VOCAB 8192

typedef _Float16 f16;
typedef __attribute__((ext_vector_type(8))) _Float16 f16x8;
typedef __attribute__((ext_vector_type(4))) _Float16 f16x4;
typedef __attribute__((ext_vector_type(4))) float f32x4;
typedef __attribute__((ext_vector_type(16))) float f32x16;

// ---------------- workspace layout (float units) ----------------
constexpr size_t OFF_EHL  = 0;           // 1,310,720 fl: e hi/lo f16 [5][8192][64f16]
constexpr size_t OFF_WF   = 1310720;     // 53,760 fl: wfrag f16 [5][7][2][3][64][8]
constexpr size_t OFF_PA   = 1364480;     // 1,572,864: [b][192][2] pass-A stats
constexpr size_t OFF_PB   = 2937344;     // 1,572,864: [b][192][2] pooled stats
constexpr size_t OFF_BN1  = 4510208;     // 320 (SoA A[160], B[160])
constexpr size_t OFF_BNP  = 4510528;     // 320
constexpr size_t OFF_CP   = 4510848;     // 131,072 floats: colstats [2048][32][2]
constexpr size_t OFF_BNF1 = 4641920;     // 4,096
constexpr size_t OFF_PRAW = 4646016;     // 7,864,320: p fp32 -> packed {hi,lo} f16 in place
constexpr size_t OFF_W1P  = 12510336;    // 1,966,080 (f16)
constexpr size_t OFF_W2P  = 14476416;    // 2,097,152 (f16)
constexpr size_t OFF_Y    = 16573568;    // 8,388,608
constexpr size_t OFF_BNF2 = 24962176;    // 4,096
constexpr size_t OFF_Z2K  = 0;           // conv region dead by then
constexpr size_t OFF_Z3K  = 4194304;     // overlaps dead conv-era buffers (order-safe)
// END = 24,966,272 fl = 99.9MB (proven available)

__device__ __forceinline__ float qw(float w) {
  return rintf(fminf(fmaxf(w, -1.f), 1.f));
}
__device__ __forceinline__ float4 ld4(const float* p) {
  return *reinterpret_cast<const float4*>(p);
}
__device__ __forceinline__ float tanh_c(float u) {
  const float e = __expf(2.f*u);
  return 1.f - __fdividef(2.f, e + 1.f);
}

#define MF(A,B,C) __builtin_amdgcn_mfma_f32_32x32x16_f16(A,B,C,0,0,0)
// w-frag fetch: variant V: 0=wh*2048, 1=(w-wh)*2048, 2=wh
#define WV(K,KS,V) (*reinterpret_cast<const f16x8*>(wfsl + (((K)*2+(KS))*3+(V))*256 + lane*4))

// ---------------- merged prep: e-table (blocks 0..5119) + w-frags (5120..5539) ----------------
__global__ __launch_bounds__(256) void k_prep(const float* __restrict__ emb,
                                              const float* __restrict__ convw,
                                              f16* __restrict__ ehl,
                                              f16* __restrict__ wf)
{
  const int bid = blockIdx.x;
  const int tid = threadIdx.x;
  if (bid < 5120) {
    const int idx = bid*256 + tid;                  // exactly 1,310,720
    const int c = idx & 31, v = (idx >> 5) & 8191, slice = idx >> 18;
    const float val = emb[(size_t)(slice*VOCAB + v)*32 + c];
    const f16 hi = (f16)val;
    const f16 lo = (f16)((val - (float)hi)*2048.f);
    f16* row = ehl + (size_t)(slice*VOCAB + v)*64;
    row[c] = hi; row[32 + c] = lo;
  } else {
    const int idx = (bid - 5120)*256 + tid;         // exactly 107,520
    const int j = idx & 7, lane = (idx >> 3) & 63;
    const int rest = idx >> 9;
    const int v = rest % 3;
    const int rest2 = rest / 3;
    const int ks = rest2 & 1, kk = rest2 >> 1;
    const int k = kk % 7, slice = kk / 7;
    const int f = lane & 31, c = ks*16 + (lane >> 5)*8 + j;
    const float val = convw[((slice*32 + f)*32 + c)*7 + k];
    const f16 hi = (f16)val;
    f16 o;
    if (v == 0)      o = (f16)((float)hi * 2048.f); // exact: exponent shift
    else if (v == 1) o = (f16)((val - (float)hi)*2048.f);
    else             o = hi;
    wf[idx] = o;
  }
}

// ---------------- MFMA conv (r14 verbatim: coalesced reg-staged gather) ----------------
// PASS 0: BN1 stats via f16 hstat transpose (r8-validated).
// PASS 1: BN1 + tanh + avgpool -> z + pooled stats.
// acc = sum over k,ks of [wh2*eh + wl*eh + wh*el] == 2048*h; h = acc/2048.
template<int PASS>
__global__ __launch_bounds__(256, 4) void k_convm(const int* __restrict__ x,
                                                  const int* __restrict__ gshift,
                                                  const float* __restrict__ ehl,
                                                  const float* __restrict__ wfrag,
                                                  const float* __restrict__ bn1,
                                                  float* __restrict__ z,
                                                  float* __restrict__ partials)
{
  const int b = blockIdx.x;
  const int type = blockIdx.y;                      // 0..3
  const int tid = threadIdx.x;
  const int wid = tid >> 6, lane = tid & 63;
  const int lt = lane & 31, hf = lane >> 5;

  __shared__ float smem[9408];
  __shared__ int   tokoff[294];                     // pre-scaled (sl*VOCAB+tok)*32 fl-offset

  float* tokarr = smem;
  f16*   hstat  = (f16*)smem;
  float* part2  = smem + 6000;
  float* thbuf  = smem;
  float* poolb  = smem + 4224;

  const int gsv = gshift[b];
  const int NTOK = (type == 0) ? 270 : 294;

  // ---- stage token ids -> pre-scaled e-table offsets ----
  for (int i = tid; i < NTOK; i += 256) {
    int xs, q = i, sl;
    if (type == 0) {
      if (i < 42)       { xs = 548; sl = 0; }
      else if (i < 120) { xs = 512; q = i - 42; sl = 1; }
      else              { xs = 440 - gsv % 12; q = i - 120; sl = 2; }
    } else if (type == 1) { xs = 296 - gsv % 24; sl = 3; }
    else if (type == 2)   { xs = 8 - gsv % 48; sl = 4; }
    else                  { xs = 8 - gsv % 48 + 288; sl = 4; }
    int xi = xs + q; if (xi < 0) xi += HTOT;
    tokoff[i] = (sl*VOCAB + x[b*HTOT + xi])*32;
  }
  __syncthreads();
  // ---- gather e rows: coalesced (8 lanes per 128B row), class-major LDS dest ----
  for (int j = tid; j < NTOK*8; j += 256) {
    const int row = j >> 3, ch = j & 7;
    const float4 v = ld4(ehl + tokoff[row] + ch*4);
    *reinterpret_cast<float4*>(&tokarr[ch*1176 + row*4]) = v;
  }
  __syncthreads();

  // ---- per-wave work assignment ----
  int slice, tb, nt, slotoff, ThV, pw, si;
  if (type == 0) {
    if      (wid == 0) { slice=0; tb=0;  nt=2; slotoff=0;   ThV=36;  pw=3;  si=0; }
    else if (wid == 1) { slice=1; tb=0;  nt=3; slotoff=42;  ThV=72;  pw=6;  si=1; }
    else if (wid == 2) { slice=2; tb=0;  nt=3; slotoff=120; ThV=144; pw=12; si=2; }
    else               { slice=2; tb=96; nt=2; slotoff=120; ThV=144; pw=12; si=2; }
  } else if (type == 1) {
    slice=3; pw=24; ThV=288; slotoff=0; si=0;
    tb = (wid == 0) ? 0 : 32 + wid*64; nt = (wid == 0) ? 3 : 2;
  } else if (type == 2) {
    slice=4; pw=48; ThV=288; slotoff=0; si=0;
    tb = (wid == 0) ? 0 : 32 + wid*64; nt = (wid == 0) ? 3 : 2;
  } else {
    slice=4; pw=48; ThV=576; slotoff=-288; si=0;
    tb = 288 + ((wid == 0) ? 0 : 32 + wid*64); nt = (wid == 0) ? 3 : 2;
  }
  const int wb = (type == 3) ? 6 : 0;
  const int slot0 = (type == 0) ? ((wid == 0) ? 0 : (wid == 1) ? 2 : (wid == 2) ? 5 : 8)
                                : ((wid == 0) ? 0 : 1 + wid*2);

  const float* wfsl = wfrag + slice*10752;          // 7*2*3*64*8 f16 = 10752 fl per slice

  f32x16 acc[3];
  #pragma unroll
  for (int r = 0; r < 3; ++r)
    #pragma unroll
    for (int i = 0; i < 16; ++i) acc[r][i] = 0.f;

  // ---- K loop ----
  const float* pb = tokarr + hf*1176 + (size_t)(slotoff + tb + lt)*4;
  #pragma unroll 1
  for (int k = 0; k < 7; ++k) {
    const f16x8 wh2_0 = WV(k,0,0), wl_0 = WV(k,0,1), wh_0 = WV(k,0,2);
    const f16x8 wh2_1 = WV(k,1,0), wl_1 = WV(k,1,1), wh_1 = WV(k,1,2);
    #pragma unroll
    for (int r = 0; r < 3; ++r) if (r < nt) {
      const float* rp = pb + k*4 + r*128;
      const f16x8 bh0 = *(const f16x8*)(rp);
      const f16x8 bh1 = *(const f16x8*)(rp + 2352);
      const f16x8 bl0 = *(const f16x8*)(rp + 4704);
      const f16x8 bl1 = *(const f16x8*)(rp + 7056);
      acc[r] = MF(wh2_0, bh0, acc[r]);
      acc[r] = MF(wl_0,  bh0, acc[r]);
      acc[r] = MF(wh_0,  bl0, acc[r]);
      acc[r] = MF(wh2_1, bh1, acc[r]);
      acc[r] = MF(wl_1,  bh1, acc[r]);
      acc[r] = MF(wh_1,  bl1, acc[r]);
    }
  }
  __syncthreads();                                  // tokarr dead -> epilogue buffers

  if (PASS == 0) {
    // ---- stats via f16 LDS transpose (validated noise class) ----
    #pragma unroll
    for (int r = 0; r < 3; ++r) if (r < nt) {
      const int tbg = tb + r*32;
      const int slot = slot0 + r;
      #pragma unroll
      for (int i = 0; i < 16; ++i) {
        const int fr = (i&3) + 8*(i>>2) + 4*hf;
        const float h = acc[r][i]*(1.f/2048.f);
        const float hv = (tbg + lt < ThV) ? h : 0.f;
        hstat[slot*1088 + fr*34 + lt] = (f16)hv;
      }
    }
    __syncthreads();
    const int nslot = (type == 0) ? 10 : 9;
    for (int j = tid; j < nslot*32; j += 256) {
      const int slot = j >> 5, f = j & 31;
      const f16* rowp = hstat + slot*1088 + f*34;
      float s1 = 0.f, s2 = 0.f;
      #pragma unroll
      for (int t = 0; t < 32; ++t) { const float v = (float)rowp[t]; s1 += v; s2 += v*v; }
      part2[(slot*32 + f)*2]     = s1;
      part2[(slot*32 + f)*2 + 1] = s2;
    }
    __syncthreads();
    const int nch = (type == 0) ? 96 : 32;
    if (tid < nch) {
      const int sic = tid >> 5, f = tid & 31;
      int slo, shi, Pb;
      if (type == 0) {
        slo = (sic == 0) ? 0 : (sic == 1) ? 2 : 5;
        shi = (sic == 0) ? 2 : (sic == 1) ? 5 : 10;
        Pb  = sic*32;
      } else { slo = 0; shi = 9; Pb = 96 + (type - 1)*32; }
      float s1 = 0.f, s2 = 0.f;
      for (int s = slo; s < shi; ++s) {
        s1 += part2[(s*32 + f)*2];
        s2 += part2[(s*32 + f)*2 + 1];
      }
      partials[(size_t)b*384 + (Pb + f)*2]     = s1;
      partials[(size_t)b*384 + (Pb + f)*2 + 1] = s2;
    }
    return;
  }

  // ---- PASS 1: BN1 + tanh + pool (poolb init via exclusive-ownership writes) ----
  float A1v[16], B1v[16];
  #pragma unroll
  for (int i = 0; i < 16; ++i) {
    const int fr = (i&3) + 8*(i>>2) + 4*hf;
    A1v[i] = bn1[slice*32 + fr];
    B1v[i] = bn1[160 + slice*32 + fr];
  }

  #pragma unroll
  for (int r = 0; r < 3; ++r) if (r < nt) {
    const int tbg = tb + r*32;
    #pragma unroll
    for (int i = 0; i < 16; ++i) {
      const int fr = (i&3) + 8*(i>>2) + 4*hf;
      const float h = acc[r][i]*(1.f/2048.f);
      thbuf[wid*1056 + fr*33 + lt] = tanh_c(A1v[i]*h + B1v[i]);
    }
    const int tvend = min(tbg + 32, ThV);
    const int wlo = tbg / pw, whi = (tvend - 1) / pw;
    for (int w = wlo; w <= whi; ++w) {
      const int lo = max(w*pw, tbg), hi2 = min((w+1)*pw, tvend);
      float s = 0.f;
      for (int t = lo + hf; t < hi2; t += 2) s += thbuf[wid*1056 + lt*33 + (t - tbg)];
      s += __shfl_xor(s, 32);
      if (hf == 0) {
        const int piece = (w*pw < tbg) ? 1 : 0;
        poolb[(si*12 + (w - wb))*64 + piece*32 + lt] = s;
        // window fully inside my region -> no later tile writes piece1: zero it here.
        if (piece == 0 && (w+1)*pw <= tvend)
          poolb[(si*12 + (w - wb))*64 + 32 + lt] = 0.f;
      }
    }
  }
  __syncthreads();

  const int nch = (type == 0) ? 96 : 32;
  if (tid < nch) {
    const int sic = tid >> 5, f = tid & 31;
    const int sg = (type == 0) ? sic : ((type == 1) ? 3 : 4);
    const int P = (sg < 4) ? sg*32 + f : ((type == 2) ? 128 + f : 160 + f);
    const int pwc = (type == 0) ? ((sic == 0) ? 3 : (sic == 1) ? 6 : 12)
                                : ((type == 1) ? 24 : 48);
    const int nwin = (type >= 2) ? 6 : 12;
    const int wbc = (type == 3) ? 6 : 0;
    const float inv = 1.f/(float)pwc;
    float s1 = 0.f, s2 = 0.f;
    for (int wl = 0; wl < nwin; ++wl) {
      const float p = (poolb[(sic*12 + wl)*64 + f] + poolb[(sic*12 + wl)*64 + 32 + f]) * inv;
      z[(size_t)b*1920 + sg*384 + (wl + wbc)*32 + f] = p;
      s1 += p; s2 += p*p;
    }
    partials[(size_t)b*384 + P*2]     = s1;
    partials[(size_t)b*384 + P*2 + 1] = s2;
  }
}

// ---------------- BN stat reduce -> SoA {A=g*rstd, B=beta-A*m} ----------------
template<int PASS>
__global__ __launch_bounds__(256) void k_bnfinal(const float* __restrict__ partials,
                                                 const float* __restrict__ gamma,
                                                 const float* __restrict__ beta,
                                                 float* __restrict__ outAB)
{
  const int c = blockIdx.x;                        // 0..159
  const int slice = c >> 5, f = c & 31;
  const int tid = threadIdx.x;
  double s1 = 0.0, s2 = 0.0;
  for (int b = tid; b < BATCH; b += 256) {
    const float* p = partials + (size_t)b*384;
    if (slice < 4) { s1 += p[(slice*32+f)*2]; s2 += p[(slice*32+f)*2+1]; }
    else {
      s1 += (double)p[(128+f)*2]   + (double)p[(160+f)*2];
      s2 += (double)p[(128+f)*2+1] + (double)p[(160+f)*2+1];
    }
  }
  __shared__ double r1[256], r2[256];
  r1[tid] = s1; r2[tid] = s2;
  __syncthreads();
  for (int off = 128; off > 0; off >>= 1) {
    if (tid < off) { r1[tid] += r1[tid+off]; r2[tid] += r2[tid+off]; }
    __syncthreads();
  }
  if (tid == 0) {
    long N;
    if (PASS == 0) { const long Tall[5] = {36,72,144,288,576}; N = (long)BATCH * Tall[slice]; }
    else           { N = (long)BATCH * 12; }
    const double m   = r1[0]/(double)N;
    const double var = r2[0]/(double)N - m*m;
    const float rstd = (float)(1.0/sqrt(var + 1e-5));
    const float Aa = gamma[c]*rstd;
    outAB[c]       = Aa;
    outAB[160 + c] = beta[c] - Aa*(float)m;
  }
}

// ---------------- pooled BN apply + in-place f16 hi/lo pack ----------------
__global__ __launch_bounds__(256) void k_znorm(float* __restrict__ zz,
                                               const float* __restrict__ bnp)
{
  const size_t i4 = (size_t)blockIdx.x*256 + threadIdx.x;  // exactly 1,966,080
  const float4 v = ld4(zz + i4*4);
  const int j = (int)((i4*4) % 1920);
  const int slice = j / 384, f0 = j & 31;
  const float4 A = ld4(bnp + slice*32 + f0);
  const float4 B = ld4(bnp + 160 + slice*32 + f0);
  const float zn[4] = {v.x*A.x+B.x, v.y*A.y+B.y, v.z*A.z+B.z, v.w*A.w+B.w};
  uint4 pk;
  unsigned w[4];
  #pragma unroll
  for (int e = 0; e < 4; ++e) {
    const f16 hi = (f16)zn[e];
    const f16 lo = (f16)(zn[e] - (float)hi);
    w[e] = (unsigned)__builtin_bit_cast(unsigned short, hi)
         | ((unsigned)__builtin_bit_cast(unsigned short, lo) << 16);
  }
  pk.x = w[0]; pk.y = w[1]; pk.z = w[2]; pk.w = w[3];
  *reinterpret_cast<uint4*>(zz + i4*4) = pk;
}

// ---------------- weight prep ----------------
__global__ __launch_bounds__(256) void k_wprep1(const float* __restrict__ W1,
                                                f16* __restrict__ W1p)
{
  const int idx = blockIdx.x*256 + threadIdx.x;    // < 3,932,160
  const int n = idx / 1920, klds = idx - n*1920;
  const int slice = klds / 384, r = klds - slice*384;
  const int tp = r >> 5, f = r & 31;
  W1p[idx] = (f16)qw(W1[n*1920 + slice*384 + f*12 + tp]);
}

__global__ __launch_bounds__(256) void k_wprep2(const float* __restrict__ W2,
                                                f16* __restrict__ W2p)
{
  const size_t i4 = (size_t)blockIdx.x*256 + threadIdx.x;  // < 1,048,576
  const float4 v = ld4(W2 + i4*4);
  f16x4 o;
  o[0] = (f16)qw(v.x); o[1] = (f16)qw(v.y); o[2] = (f16)qw(v.z); o[3] = (f16)qw(v.w);
  *reinterpret_cast<f16x4*>(&W2p[i4*4]) = o;
}

// ---------------- MFMA GEMM with fused per-block column stats (r11-validated) ----------------
template<int SPLIT, int PACKED>
__global__ __launch_bounds__(256) void k_mfgemm(const f16* __restrict__ Ahi,
                                               const unsigned* __restrict__ Apk,
                                               const f16* __restrict__ Bp,
                                               float* __restrict__ C,
                                               float* __restrict__ cpart,
                                               const int K, const float oscale)
{
  __shared__ f16 sA[(SPLIT+1)*128][40];
  __shared__ f16 sB[128][40];
  __shared__ float cst[4][4][16][2];
  const int tid = threadIdx.x;
  const int bm = blockIdx.y*128, bn = blockIdx.x*128;
  const int wid = tid >> 6, lane = tid & 63;
  const int wm = (wid >> 1)*64, wn = (wid & 1)*64;
  const int lgrp = lane >> 4, lrow = lane & 15;
  f32x4 acc[4][4];
  #pragma unroll
  for (int m = 0; m < 4; ++m)
    #pragma unroll
    for (int n = 0; n < 4; ++n) acc[m][n] = (f32x4){0.f,0.f,0.f,0.f};

  const int srow = tid >> 2, sc = (tid & 3)*8;
  for (int k0 = 0; k0 < K; k0 += 32) {
    #pragma unroll
    for (int u = 0; u < 2; ++u) {
      const int row = srow + u*64;
      if (PACKED) {
        const unsigned* ap = Apk + (size_t)(bm+row)*K + k0 + sc;
        const uint4 v0 = *reinterpret_cast<const uint4*>(ap);
        const uint4 v1 = *reinterpret_cast<const uint4*>(ap + 4);
        uint4 hi, lo;
        hi.x = (v0.x & 0xffffu) | (v0.y << 16);  hi.y = (v0.z & 0xffffu) | (v0.w << 16);
        hi.z = (v1.x & 0xffffu) | (v1.y << 16);  hi.w = (v1.z & 0xffffu) | (v1.w << 16);
        lo.x = (v0.x >> 16) | (v0.y & 0xffff0000u);  lo.y = (v0.z >> 16) | (v0.w & 0xffff0000u);
        lo.z = (v1.x >> 16) | (v1.y & 0xffff0000u);  lo.w = (v1.z >> 16) | (v1.w & 0xffff0000u);
        *reinterpret_cast<uint4*>(&sA[row][sc])     = hi;
        *reinterpret_cast<uint4*>(&sA[128+row][sc]) = lo;
      } else {
        const uint4 va = *reinterpret_cast<const uint4*>(&Ahi[(size_t)(bm+row)*K + k0 + sc]);
        *reinterpret_cast<uint4*>(&sA[row][sc]) = va;
      }
      const uint4 vb = *reinterpret_cast<const uint4*>(&Bp[(size_t)(bn+row)*K + k0 + sc]);
      *reinterpret_cast<uint4*>(&sB[row][sc]) = vb;
    }
    __syncthreads();
    f16x8 bf[4];
    #pragma unroll
    for (int n = 0; n < 4; ++n)
      bf[n] = *reinterpret_cast<const f16x8*>(&sB[wn + n*16 + lrow][lgrp*8]);
    #pragma unroll
    for (int m = 0; m < 4; ++m) {
      const f16x8 ah = *reinterpret_cast<const f16x8*>(&sA[wm + m*16 + lrow][lgrp*8]);
      #pragma unroll
      for (int n = 0; n < 4; ++n)
        acc[m][n] = __builtin_amdgcn_mfma_f32_16x16x32_f16(ah, bf[n], acc[m][n], 0, 0, 0);
      if (SPLIT) {
        const f16x8 al = *reinterpret_cast<const f16x8*>(&sA[128 + wm + m*16 + lrow][lgrp*8]);
        #pragma unroll
        for (int n = 0; n < 4; ++n)
          acc[m][n] = __builtin_amdgcn_mfma_f32_16x16x32_f16(al, bf[n], acc[m][n], 0, 0, 0);
      }
    }
    __syncthreads();
  }
  float s1[4] = {0,0,0,0}, s2[4] = {0,0,0,0};
  #pragma unroll
  for (int m = 0; m < 4; ++m)
    #pragma unroll
    for (int n = 0; n < 4; ++n) {
      const int col = bn + wn + n*16 + lrow;
      #pragma unroll
      for (int r = 0; r < 4; ++r) {
        const float v = acc[m][n][r]*oscale;
        C[(size_t)(bm + wm + m*16 + lgrp*4 + r)*2048 + col] = v;
        s1[n] += v; s2[n] += v*v;
      }
    }
  #pragma unroll
  for (int n = 0; n < 4; ++n) {
    s1[n] += __shfl_xor(s1[n], 16); s1[n] += __shfl_xor(s1[n], 32);
    s2[n] += __shfl_xor(s2[n], 16); s2[n] += __shfl_xor(s2[n], 32);
  }
  if (lgrp == 0) {
    #pragma unroll
    for (int n = 0; n < 4; ++n) { cst[wid][n][lrow][0] = s1[n]; cst[wid][n][lrow][1] = s2[n]; }
  }
  __syncthreads();
  if (tid < 128) {
    const int n = tid >> 5, half = (tid >> 4) & 1, lr = tid & 15;
    const float a1 = cst[half][n][lr][0] + cst[half+2][n][lr][0];
    const float a2 = cst[half][n][lr][1] + cst[half+2][n][lr][1];
    const int col = bn + half*64 + n*16 + lr;
    cpart[(size_t)col*64 + blockIdx.y*2]     = a1;
    cpart[(size_t)col*64 + blockIdx.y*2 + 1] = a2;
  }
}

// ---------------- column stat finalize (32 float chunks -> BN A/B) ----------------
__global__ __launch_bounds__(256) void k_colfinal(const float* __restrict__ part,
                                                  const float* __restrict__ gamma,
                                                  const float* __restrict__ beta,
                                                  float* __restrict__ bnfc, int N)
{
  const int c = blockIdx.x*256 + threadIdx.x;
  if (c >= N) return;
  double s1 = 0.0, s2 = 0.0;
  #pragma unroll
  for (int ch = 0; ch < 32; ++ch) {
    s1 += (double)part[(size_t)c*64 + ch*2];
    s2 += (double)part[(size_t)c*64 + ch*2 + 1];
  }
  const double m   = s1/4096.0;
  const double var = s2/4096.0 - m*m;
  const float rstd = (float)(1.0/sqrt(var + 1e-5));
  const float Aa = gamma[c]*rstd;
  bnfc[c]        = Aa;
  bnfc[2048 + c] = beta[c] - Aa*(float)m;
}

// ---------------- BN + hardtanh + quantize -> integer k in f16 ----------------
__global__ __launch_bounds__(256) void k_act(const float* __restrict__ Y,
                                             const float* __restrict__ bnfc,
                                             f16* __restrict__ Zk)
{
  const size_t i4 = (size_t)blockIdx.x*256 + threadIdx.x;  // exactly 2,097,152
  const int cbase = (int)((i4*4) & 2047);
  const float4 v = ld4(Y + i4*4);
  const float4 A = ld4(bnfc + cbase);
  const float4 B = ld4(bnfc + 2048 + cbase);
  const float t[4] = {v.x*A.x+B.x, v.y*A.y+B.y, v.z*A.z+B.z, v.w*A.w+B.w};
  f16x4 o;
  #pragma unroll
  for (int e = 0; e < 4; ++e) {
    const float c = fminf(fmaxf(t[e], -1.f), 1.f);
    o[e] = (f16)rintf(c*3.f);
  }
  *reinterpret_cast<f16x4*>(&Zk[i4*4]) = o;
}

// ---------------- final dot ----------------
__global__ __launch_bounds__(256) void k_final(const f16* __restrict__ Z3,
                                               const float* __restrict__ W3,
                                               const float* __restrict__ b3,
                                               float* __restrict__ out)
{
  const int b = blockIdx.x;
  const int tid = threadIdx.x;
  float s = 0.f;
  for (int j = tid; j < 2048; j += 256)
    s += (float)Z3[(size_t)b*2048 + j] * qw(W3[j]);
  __shared__ float red[256];
  red[tid] = s;
  __syncthreads();
  for (int off = 128; off > 0; off >>= 1) {
    if (tid < off) red[tid] += red[tid+off];
    __syncthreads();
  }
  if (tid == 0) out[b] = red[0]*(1.f/3.f) + b3[0];
}

extern "C" void kernel_launch(void* const* d_in, const int* in_sizes, int n_in,
                              void* d_out, int out_size, void* d_ws, size_t ws_size,
                              hipStream_t stream)
{
  const int*   x    = (const int*)d_in[0];
  const int*   gs   = (const int*)d_in[1];
  const float* emb  = (const float*)d_in[2];
  const float* cw   = (const float*)d_in[3];
  const float* bn1g = (const float*)d_in[5];
  const float* bn1b = (const float*)d_in[6];
  const float* bnpg = (const float*)d_in[7];
  const float* bnpb = (const float*)d_in[8];
  const float* W1   = (const float*)d_in[9];
  const float* g1   = (const float*)d_in[11];
  const float* be1  = (const float*)d_in[12];
  const float* W2   = (const float*)d_in[13];
  const float* g2   = (const float*)d_in[15];
  const float* be2  = (const float*)d_in[16];
  const float* W3   = (const float*)d_in[17];
  const float* b3   = (const float*)d_in[18];
  float* ws  = (float*)d_ws;
  float* out = (float*)d_out;

  k_prep<<<5540, 256, 0, stream>>>(emb, cw, (f16*)(ws + OFF_EHL), (f16*)(ws + OFF_WF));

  k_convm<0><<<dim3(BATCH, 4), 256, 0, stream>>>(x, gs, ws + OFF_EHL, ws + OFF_WF,
                                                 ws + OFF_BN1, nullptr, ws + OFF_PA);
  k_bnfinal<0><<<160, 256, 0, stream>>>(ws + OFF_PA, bn1g, bn1b, ws + OFF_BN1);
  k_convm<1><<<dim3(BATCH, 4), 256, 0, stream>>>(x, gs, ws + OFF_EHL, ws + OFF_WF,
                                                 ws + OFF_BN1, ws + OFF_PRAW, ws + OFF_PB);
  k_bnfinal<1><<<160, 256, 0, stream>>>(ws + OFF_PB, bnpg, bnpb, ws + OFF_BNP);
  k_znorm<<<7680, 256, 0, stream>>>(ws + OFF_PRAW, ws + OFF_BNP);
  k_wprep1<<<15360, 256, 0, stream>>>(W1, (f16*)(ws + OFF_W1P));
  k_wprep2<<<4096, 256, 0, stream>>>(W2, (f16*)(ws + OFF_W2P));

  k_mfgemm<1,1><<<dim3(16, 32), 256, 0, stream>>>(nullptr, (const unsigned*)(ws + OFF_PRAW),
                                                  (const f16*)(ws + OFF_W1P),
                                                  ws + OFF_Y, ws + OFF_CP, 1920, 1.f);
  k_colfinal<<<8, 256, 0, stream>>>(ws + OFF_CP, g1, be1, ws + OFF_BNF1, 2048);
  k_act<<<8192, 256, 0, stream>>>(ws + OFF_Y, ws + OFF_BNF1, (f16*)(ws + OFF_Z2K));

  k_mfgemm<0,0><<<dim3(16, 32), 256, 0, stream>>>((const f16*)(ws + OFF_Z2K), nullptr,
                                                  (const f16*)(ws + OFF_W2P),
                                                  ws + OFF_Y, ws + OFF_CP, 2048, 1.f/3.f);
  k_colfinal<<<8, 256, 0, stream>>>(ws + OFF_CP, g2, be2, ws + OFF_BNF2, 2048);
  k_act<<<8192, 256, 0, stream>>>(ws + OFF_Y, ws + OFF_BNF2, (f16*)(ws + OFF_Z3K));

  k_final<<<4096, 256, 0, stream>>>((const f16*)(ws + OFF_Z3K), W3, b3, out);
}